// Round 13
// baseline (85.419 us; speedup 1.0000x reference)
//
#include <hip/hip_runtime.h>
#include <math.h>

// ---------------------------------------------------------------------------
// ConvLogicNetCIFAR forward. R13 = R11 mega (conv tower only) + FC moved to
// its own full-chip dispatch.
// Evidence trail: mega is a serial pipeline on half the chip (128 blocks =
// batch size; cross-block sync is dead per R8/R10 L2-flush finding). R12
// showed bank conflicts were NOT the limiter (conflicts -32%, time +3%).
// So: shorten the serial path. The FC phase (10240 gate trees) only needs
// stage4's 8KB output and is embarrassingly parallel -> third kernel,
// 1280 blocks (128 batch x 10 classes) x 256 thr, S4 staged to LDS, 4 trees
// per thread, one deterministic store per block (no atomics).
// mega keeps R11's stage code (best so far: 63.1us) minus FC; stage4 writes
// S4 to global coalesced (8KB/block).
// Gate: c0 + c1*a + c2*b + c3*(a*b), c = softmax(w_row)@COEF.
// Conv tree quirk: off=2^lvl-1 -> level0 rows0..3, level1 rows1..2, level2 row3.
// ---------------------------------------------------------------------------

typedef _Float16 h16;
typedef _Float16 h2 __attribute__((ext_vector_type(2)));

__constant__ float c_coef_tbl[16][4] = {
    {0, 0, 0, 0}, {0, 0, 0, 1}, {0, 1, 0, -1}, {0, 1, 0, 0},
    {0, 0, 1, -1}, {0, 0, 1, 0}, {0, 1, 1, -2}, {0, 1, 1, -1},
    {1, -1, -1, 1}, {1, -1, -1, 2}, {1, 0, -1, 0}, {1, 0, -1, 1},
    {1, -1, 0, 0}, {1, -1, 0, 1}, {1, 0, 0, -1}, {1, 0, 0, 0}};

__device__ __forceinline__ float4 softmax_coef(const float* __restrict__ wr) {
  float m = -1e30f;
#pragma unroll
  for (int k = 0; k < 16; ++k) m = fmaxf(m, wr[k]);
  float e[16], s = 0.f;
#pragma unroll
  for (int k = 0; k < 16; ++k) { e[k] = __expf(wr[k] - m); s += e[k]; }
  float inv = 1.f / s;
  float c0 = 0.f, c1 = 0.f, c2 = 0.f, c3 = 0.f;
#pragma unroll
  for (int k = 0; k < 16; ++k) {
    c0 += e[k] * c_coef_tbl[k][0];
    c1 += e[k] * c_coef_tbl[k][1];
    c2 += e[k] * c_coef_tbl[k][2];
    c3 += e[k] * c_coef_tbl[k][3];
  }
  return make_float4(c0 * inv, c1 * inv, c2 * inv, c3 * inv);
}

__device__ __forceinline__ float gate_eval(float4 c, float a, float b) {
  return c.x + c.y * a + c.z * b + c.w * (a * b);
}
__device__ __forceinline__ float4 dec_cf(uint2 u) {
  h2 p0, p1;
  *(unsigned*)&p0 = u.x;
  *(unsigned*)&p1 = u.y;
  return make_float4((float)p0[0], (float)p0[1], (float)p1[0], (float)p1[1]);
}
__device__ __forceinline__ h2 gateh(const h2* c, h2 a, h2 b) {
  return c[0] + c[1] * a + c[2] * b + c[3] * (a * b);
}

// prep: g<71680 FC tree (o=g/7, s=g%7 -> fp16 coefs mcoefh[o*28+s*4], u16
// midx16[o*8..]); g in [71680,78464) conv gate coefs float4
// (w1[0,128) w2[128,640) w3[640,2688) w4[2688,6784); gate gg -> row oc*7+(gg&3)).
__global__ void prep_all(const float* __restrict__ w1, const float* __restrict__ w2,
                         const float* __restrict__ w3, const float* __restrict__ w4,
                         const float* __restrict__ fw1, const float* __restrict__ fw2,
                         const float* __restrict__ fw3,
                         const int* __restrict__ ca1, const int* __restrict__ cb1,
                         const int* __restrict__ ca2, const int* __restrict__ cb2,
                         const int* __restrict__ ca3, const int* __restrict__ cb3,
                         float4* __restrict__ coefC,
                         unsigned short* __restrict__ midx16,
                         _Float16* __restrict__ mcoefh) {
  int g = blockIdx.x * blockDim.x + threadIdx.x;
  if (g < 71680) {
    int o = g / 7;
    int s = g - o * 7;
    float4 c;
    if (s < 4) {
      int k = (s < 2) ? ca3[o] : cb3[o];
      int j = (s & 1) ? cb2[k] : ca2[k];
      midx16[o * 8 + s * 2]     = (unsigned short)ca1[j];
      midx16[o * 8 + s * 2 + 1] = (unsigned short)cb1[j];
      c = softmax_coef(fw1 + j * 16);
    } else if (s < 6) {
      int k = (s == 4) ? ca3[o] : cb3[o];
      c = softmax_coef(fw2 + k * 16);
    } else {
      c = softmax_coef(fw3 + o * 16);
    }
    _Float16* mc = mcoefh + o * 28 + s * 4;
    mc[0] = (_Float16)c.x; mc[1] = (_Float16)c.y;
    mc[2] = (_Float16)c.z; mc[3] = (_Float16)c.w;
  } else if (g < 78464) {
    int gg = g - 71680;
    int base = gg;
    const float* w;
    if (gg < 128)       {             w = w1; }
    else if (gg < 640)  { gg -= 128;  w = w2; }
    else if (gg < 2688) { gg -= 640;  w = w3; }
    else                { gg -= 2688; w = w4; }
    coefC[base] = softmax_coef(w + ((gg >> 2) * 7 + (gg & 3)) * 16);
  }
}

// Conv tree + orpool, LDS->LDS, dup-padded in; dup-padded (OUTDUP) or plain
// fp16 out.  IPS/OPS = channel-plane strides in cells.
template <int C, int H, int W, int OC, int IPS, int OPS, bool OUTDUP>
__device__ void stage(const h2* __restrict__ in, h2* __restrict__ outD,
                      h16* __restrict__ outP,
                      const int* __restrict__ leaf,
                      const float4* __restrict__ coef, int tid) {
  constexpr int Wp = W + 2;
  constexpr int PH = H / 2, PW = W / 2;
  constexpr int NPOS = PH * PW;
  constexpr int TPO = 1024 / OC;
  constexpr int ITER = NPOS / TPO;
  constexpr int OWp = PW + 2;

  int oc = tid / TPO;
  int lane = tid % TPO;

  int toff[8];
#pragma unroll
  for (int l = 0; l < 8; ++l) {
    int k = leaf[oc * 8 + l];
    int cc = k / 9;
    int p = k - 9 * cc;
    int di = p / 3;
    int dj = p - 3 * di;
    toff[l] = cc * IPS + di * Wp + dj;
  }
  h2 ch[4][4];
#pragma unroll
  for (int r = 0; r < 4; ++r) {
    float4 c = coef[oc * 4 + r];
    _Float16 x0 = (_Float16)c.x, x1 = (_Float16)c.y,
             x2 = (_Float16)c.z, x3 = (_Float16)c.w;
    ch[r][0][0] = x0; ch[r][0][1] = x0;
    ch[r][1][0] = x1; ch[r][1][1] = x1;
    ch[r][2][0] = x2; ch[r][2][1] = x2;
    ch[r][3][0] = x3; ch[r][3][1] = x3;
  }

#pragma unroll
  for (int it = 0; it < ITER; ++it) {
    int pos = lane + it * TPO;
    int pw = pos % PW, ph = pos / PW;
    h2 o01[2];
#pragma unroll
    for (int py = 0; py < 2; ++py) {
      int pbase = (2 * ph + py) * Wp + 2 * pw;
      h2 lv[8];
#pragma unroll
      for (int l = 0; l < 8; ++l) lv[l] = in[toff[l] + pbase];
      h2 t0 = gateh(ch[0], lv[0], lv[1]);
      h2 t1 = gateh(ch[1], lv[2], lv[3]);
      h2 t2 = gateh(ch[2], lv[4], lv[5]);
      h2 t3 = gateh(ch[3], lv[6], lv[7]);
      h2 u0 = gateh(ch[1], t0, t1);
      h2 u1 = gateh(ch[2], t2, t3);
      o01[py] = gateh(ch[3], u0, u1);
    }
    _Float16 m0 = o01[0][0] > o01[1][0] ? o01[0][0] : o01[1][0];
    _Float16 m1 = o01[0][1] > o01[1][1] ? o01[0][1] : o01[1][1];
    _Float16 v = m0 > m1 ? m0 : m1;
    if (OUTDUP) {
      h16* oh = (h16*)outD;
      int cell = oc * OPS + (ph + 1) * OWp + (pw + 1);
      oh[2 * cell] = v;      // lo of (ph+1, pw+1)
      oh[2 * cell - 1] = v;  // hi of (ph+1, pw)
    } else {
      outP[oc * NPOS + ph * PW + pw] = v;
    }
  }
}

// Megakernel: conv tower only. One block per batch element, 128 x 1024.
__global__ __launch_bounds__(1024) void mega(
    const float* __restrict__ x, const float4* __restrict__ coefC,
    const int* __restrict__ l1, const int* __restrict__ l2,
    const int* __restrict__ l3, const int* __restrict__ l4,
    h16* __restrict__ s4g) {
  __shared__ __align__(16) h2 XB[9 * 1157];    // 41,652B  [9][34x34 +1]
  __shared__ __align__(16) h2 S1[32 * 325];    // 41,600B  [32][18x18 +1]
  __shared__ __align__(16) h2 S2[128 * 101];   // 51,712B  [128][10x10 +1]
  __shared__ __align__(16) h16 S3[512 * 16];   // 16,384B  plain [512][4][4]
  int tid = threadIdx.x;
  int b = blockIdx.x;

  // ---- phase 0: zero S1/S2 + binarize x -> XB dup-padded ----
  {
    float4* z1 = (float4*)S1;  // 2600 float4
    float4* z2 = (float4*)S2;  // 3232 float4
    float4 zz = make_float4(0.f, 0.f, 0.f, 0.f);
    for (int i = tid; i < 2600; i += 1024) z1[i] = zz;
    for (int i = tid; i < 3232; i += 1024) z2[i] = zz;
  }
  const float* xg = x + b * 3072;
  for (int cell = tid; cell < 9 * 1157; cell += 1024) {
    int c9 = cell / 1157;
    int rem = cell - c9 * 1157;
    if (rem >= 1156) continue;  // plane pad cell, never read
    int i = rem / 34, j = rem - 34 * (rem / 34);
    int th = c9 / 3, c = c9 - 3 * th;
    float thr = (float)(th + 1) * 0.25f;
    _Float16 lo = (_Float16)0, hi = (_Float16)0;
    if (i >= 1 && i <= 32) {
      const float* row = xg + c * 1024 + (i - 1) * 32;
      if (j >= 1 && j <= 32) lo = (_Float16)((row[j - 1] > thr) ? 1.f : 0.f);
      if (j <= 31)           hi = (_Float16)((row[j] > thr) ? 1.f : 0.f);
    }
    XB[cell] = h2{lo, hi};
  }
  __syncthreads();

  // ---- conv tower ----
  stage<9, 32, 32, 32, 1157, 325, true>(XB, S1, nullptr, l1, coefC, tid);
  __syncthreads();
  stage<32, 16, 16, 128, 325, 101, true>(S1, S2, nullptr, l2, coefC + 128, tid);
  __syncthreads();
  stage<128, 8, 8, 512, 101, 0, false>(S2, nullptr, S3, l3, coefC + 640, tid);
  __syncthreads();

  // ---- stage 4: plain in [512][4][4], 1 thread/oc -> GLOBAL s4g[b][4096] ----
  {
    int oc = tid;
    int cc[8], di[8], dj[8];
#pragma unroll
    for (int l = 0; l < 8; ++l) {
      int k = l4[oc * 8 + l];
      cc[l] = k / 9;
      int p = k - 9 * cc[l];
      di[l] = p / 3;
      dj[l] = p - 3 * di[l];
    }
    float4 c0 = coefC[2688 + oc * 4 + 0];
    float4 c1 = coefC[2688 + oc * 4 + 1];
    float4 c2 = coefC[2688 + oc * 4 + 2];
    float4 c3 = coefC[2688 + oc * 4 + 3];
    h16 vout[4];
#pragma unroll
    for (int pos = 0; pos < 4; ++pos) {
      int pw = pos & 1, ph = pos >> 1;
      float best = -1e30f;
#pragma unroll
      for (int py = 0; py < 2; ++py) {
#pragma unroll
        for (int px = 0; px < 2; ++px) {
          int i = 2 * ph + py, j = 2 * pw + px;
          float lv[8];
#pragma unroll
          for (int l = 0; l < 8; ++l) {
            int ii = i + di[l] - 1, jj = j + dj[l] - 1;
            float v = 0.f;
            if ((unsigned)ii < 4u && (unsigned)jj < 4u)
              v = (float)S3[cc[l] * 16 + ii * 4 + jj];
            lv[l] = v;
          }
          float t0 = gate_eval(c0, lv[0], lv[1]);
          float t1 = gate_eval(c1, lv[2], lv[3]);
          float t2 = gate_eval(c2, lv[4], lv[5]);
          float t3 = gate_eval(c3, lv[6], lv[7]);
          float u0 = gate_eval(c1, t0, t1);
          float u1 = gate_eval(c2, t2, t3);
          best = fmaxf(best, gate_eval(c3, u0, u1));
        }
      }
      vout[pos] = (h16)best;
    }
    // one 8B coalesced store per thread
    uint2 pack;
    h2 plo{vout[0], vout[1]}, phi{vout[2], vout[3]};
    pack.x = __builtin_bit_cast(unsigned, plo);
    pack.y = __builtin_bit_cast(unsigned, phi);
    *(uint2*)(s4g + b * 4096 + oc * 4) = pack;
  }
}

// FC: one block per (batch, class). 1280 blocks x 256 thr. S4[b] staged to
// LDS (8KB), 4 trees/thread, wave+LDS reduce, single store. Deterministic.
__global__ __launch_bounds__(256) void fc_kernel(
    const h16* __restrict__ s4g,
    const unsigned short* __restrict__ midx16,
    const _Float16* __restrict__ mcoefh, float* __restrict__ out) {
  __shared__ __align__(16) h16 S4[4096];
  __shared__ float red[4];
  int tid = threadIdx.x;
  int b = blockIdx.x / 10;
  int cls = blockIdx.x - b * 10;

  {
    const uint4* src = (const uint4*)(s4g + b * 4096);
    uint4* dst = (uint4*)S4;
    dst[tid] = src[tid];
    dst[tid + 256] = src[tid + 256];
  }
  __syncthreads();

  const uint4* mi = (const uint4*)midx16;
  const uint2* mc = (const uint2*)mcoefh;
  float ysum = 0.f;
#pragma unroll
  for (int t = 0; t < 4; ++t) {
    int o = cls * 1024 + t * 256 + tid;
    uint4 I = mi[o];
    const uint2* cfp = mc + o * 7;
    float L0 = gate_eval(dec_cf(cfp[0]), (float)S4[I.x & 0xffff], (float)S4[I.x >> 16]);
    float L1 = gate_eval(dec_cf(cfp[1]), (float)S4[I.y & 0xffff], (float)S4[I.y >> 16]);
    float L2 = gate_eval(dec_cf(cfp[2]), (float)S4[I.z & 0xffff], (float)S4[I.z >> 16]);
    float L3 = gate_eval(dec_cf(cfp[3]), (float)S4[I.w & 0xffff], (float)S4[I.w >> 16]);
    float M0 = gate_eval(dec_cf(cfp[4]), L0, L1);
    float M1 = gate_eval(dec_cf(cfp[5]), L2, L3);
    ysum += gate_eval(dec_cf(cfp[6]), M0, M1);
  }
#pragma unroll
  for (int m = 32; m > 0; m >>= 1) ysum += __shfl_xor(ysum, m, 64);
  if ((tid & 63) == 0) red[tid >> 6] = ysum;
  __syncthreads();
  if (tid == 0)
    out[b * 10 + cls] = (red[0] + red[1] + red[2] + red[3]) * 0.1f;
}

extern "C" void kernel_launch(void* const* d_in, const int* in_sizes, int n_in,
                              void* d_out, int out_size, void* d_ws, size_t ws_size,
                              hipStream_t stream) {
  const float* x   = (const float*)d_in[0];
  const float* w1  = (const float*)d_in[1];
  const float* w2  = (const float*)d_in[2];
  const float* w3  = (const float*)d_in[3];
  const float* w4  = (const float*)d_in[4];
  const float* fw1 = (const float*)d_in[5];
  const float* fw2 = (const float*)d_in[6];
  const float* fw3 = (const float*)d_in[7];
  const int* l1  = (const int*)d_in[8];
  const int* l2  = (const int*)d_in[9];
  const int* l3  = (const int*)d_in[10];
  const int* l4  = (const int*)d_in[11];
  const int* ca1 = (const int*)d_in[12];
  const int* cb1 = (const int*)d_in[13];
  const int* ca2 = (const int*)d_in[14];
  const int* cb2 = (const int*)d_in[15];
  const int* ca3 = (const int*)d_in[16];
  const int* cb3 = (const int*)d_in[17];

  char* ws = (char*)d_ws;
  float4*         coefC  = (float4*)ws;                      // 108,544 B
  unsigned short* midx16 = (unsigned short*)(ws + 108544);   // 163,840 B
  _Float16*       mcoefh = (_Float16*)(ws + 272384);         // 573,440 B
  h16*            s4g    = (h16*)(ws + 845824);              // 128*4096*2 = 1MB

  prep_all<<<307, 256, 0, stream>>>(w1, w2, w3, w4, fw1, fw2, fw3,
                                    ca1, cb1, ca2, cb2, ca3, cb3,
                                    coefC, midx16, mcoefh);
  mega<<<128, 1024, 0, stream>>>(x, coefC, l1, l2, l3, l4, s4g);
  fc_kernel<<<1280, 256, 0, stream>>>(s4g, midx16, mcoefh, (float*)d_out);
}

// Round 14
// 59.503 us; speedup vs baseline: 1.4355x; 1.4355x over previous
//
#include <hip/hip_runtime.h>
#include <math.h>

// ---------------------------------------------------------------------------
// ConvLogicNetCIFAR forward. R14 = R11 (best, 63.1us) + redundant-pair FC
// split. R13 lesson: an extra dispatch costs ~10us+ of boundary/drain -- only
// worth it if it removes more serial time than that (FC didn't).
// Structure: 256 blocks x 1024 thr = 2 blocks per batch element. Both blocks
// redundantly compute the FULL conv tower in LDS (parallel -> no wall-time
// cost; uses the 128 CUs that sat idle since R7). Then each block computes 5
// of the 10 FC classes (the last serial chunk, ~10-15us, halved). No
// cross-block sync anywhere (R8/R10: any agent-scope fence = per-XCD L2
// flush, 46MB writebacks). Adjacent pair (bid>>1) -> same XCD -> shared L2.
//  - disjoint LDS regions, halo zeroing folded into phase 0 (6 barriers)
//  - pair-dup h2 cells: one ds_read_b32 = both pooled-window columns; packed
//    v_pk_fma_f16 gates; py-pair reads are ds_read2-fusable (const offset)
//  - s3/s4 plain fp16; stage4 bounds-checked, S4 aliases dead XB
// Gate: c0 + c1*a + c2*b + c3*(a*b), c = softmax(w_row)@COEF.
// Conv tree quirk: off=2^lvl-1 -> level0 rows0..3, level1 rows1..2, level2 row3.
// ---------------------------------------------------------------------------

typedef _Float16 h16;
typedef _Float16 h2 __attribute__((ext_vector_type(2)));

__constant__ float c_coef_tbl[16][4] = {
    {0, 0, 0, 0}, {0, 0, 0, 1}, {0, 1, 0, -1}, {0, 1, 0, 0},
    {0, 0, 1, -1}, {0, 0, 1, 0}, {0, 1, 1, -2}, {0, 1, 1, -1},
    {1, -1, -1, 1}, {1, -1, -1, 2}, {1, 0, -1, 0}, {1, 0, -1, 1},
    {1, -1, 0, 0}, {1, -1, 0, 1}, {1, 0, 0, -1}, {1, 0, 0, 0}};

__device__ __forceinline__ float4 softmax_coef(const float* __restrict__ wr) {
  float m = -1e30f;
#pragma unroll
  for (int k = 0; k < 16; ++k) m = fmaxf(m, wr[k]);
  float e[16], s = 0.f;
#pragma unroll
  for (int k = 0; k < 16; ++k) { e[k] = __expf(wr[k] - m); s += e[k]; }
  float inv = 1.f / s;
  float c0 = 0.f, c1 = 0.f, c2 = 0.f, c3 = 0.f;
#pragma unroll
  for (int k = 0; k < 16; ++k) {
    c0 += e[k] * c_coef_tbl[k][0];
    c1 += e[k] * c_coef_tbl[k][1];
    c2 += e[k] * c_coef_tbl[k][2];
    c3 += e[k] * c_coef_tbl[k][3];
  }
  return make_float4(c0 * inv, c1 * inv, c2 * inv, c3 * inv);
}

__device__ __forceinline__ float gate_eval(float4 c, float a, float b) {
  return c.x + c.y * a + c.z * b + c.w * (a * b);
}
__device__ __forceinline__ float4 dec_cf(uint2 u) {
  h2 p0, p1;
  *(unsigned*)&p0 = u.x;
  *(unsigned*)&p1 = u.y;
  return make_float4((float)p0[0], (float)p0[1], (float)p1[0], (float)p1[1]);
}
__device__ __forceinline__ h2 gateh(const h2* c, h2 a, h2 b) {
  return c[0] + c[1] * a + c[2] * b + c[3] * (a * b);
}

// prep: g<71680 FC tree (o=g/7, s=g%7 -> fp16 coefs mcoefh[o*28+s*4], u16
// midx16[o*8..]); g in [71680,78464) conv gate coefs float4
// (w1[0,128) w2[128,640) w3[640,2688) w4[2688,6784); gate gg -> row oc*7+(gg&3)).
__global__ void prep_all(const float* __restrict__ w1, const float* __restrict__ w2,
                         const float* __restrict__ w3, const float* __restrict__ w4,
                         const float* __restrict__ fw1, const float* __restrict__ fw2,
                         const float* __restrict__ fw3,
                         const int* __restrict__ ca1, const int* __restrict__ cb1,
                         const int* __restrict__ ca2, const int* __restrict__ cb2,
                         const int* __restrict__ ca3, const int* __restrict__ cb3,
                         float4* __restrict__ coefC,
                         unsigned short* __restrict__ midx16,
                         _Float16* __restrict__ mcoefh) {
  int g = blockIdx.x * blockDim.x + threadIdx.x;
  if (g < 71680) {
    int o = g / 7;
    int s = g - o * 7;
    float4 c;
    if (s < 4) {
      int k = (s < 2) ? ca3[o] : cb3[o];
      int j = (s & 1) ? cb2[k] : ca2[k];
      midx16[o * 8 + s * 2]     = (unsigned short)ca1[j];
      midx16[o * 8 + s * 2 + 1] = (unsigned short)cb1[j];
      c = softmax_coef(fw1 + j * 16);
    } else if (s < 6) {
      int k = (s == 4) ? ca3[o] : cb3[o];
      c = softmax_coef(fw2 + k * 16);
    } else {
      c = softmax_coef(fw3 + o * 16);
    }
    _Float16* mc = mcoefh + o * 28 + s * 4;
    mc[0] = (_Float16)c.x; mc[1] = (_Float16)c.y;
    mc[2] = (_Float16)c.z; mc[3] = (_Float16)c.w;
  } else if (g < 78464) {
    int gg = g - 71680;
    int base = gg;
    const float* w;
    if (gg < 128)       {             w = w1; }
    else if (gg < 640)  { gg -= 128;  w = w2; }
    else if (gg < 2688) { gg -= 640;  w = w3; }
    else                { gg -= 2688; w = w4; }
    coefC[base] = softmax_coef(w + ((gg >> 2) * 7 + (gg & 3)) * 16);
  }
}

// Conv tree + orpool, LDS->LDS, dup-padded in; dup-padded (OUTDUP) or plain
// fp16 out.  IPS/OPS = channel-plane strides in cells.
template <int C, int H, int W, int OC, int IPS, int OPS, bool OUTDUP>
__device__ void stage(const h2* __restrict__ in, h2* __restrict__ outD,
                      h16* __restrict__ outP,
                      const int* __restrict__ leaf,
                      const float4* __restrict__ coef, int tid) {
  constexpr int Wp = W + 2;
  constexpr int PH = H / 2, PW = W / 2;
  constexpr int NPOS = PH * PW;
  constexpr int TPO = 1024 / OC;
  constexpr int ITER = NPOS / TPO;
  constexpr int OWp = PW + 2;

  int oc = tid / TPO;
  int lane = tid % TPO;

  int toff[8];
#pragma unroll
  for (int l = 0; l < 8; ++l) {
    int k = leaf[oc * 8 + l];
    int cc = k / 9;
    int p = k - 9 * cc;
    int di = p / 3;
    int dj = p - 3 * di;
    toff[l] = cc * IPS + di * Wp + dj;
  }
  h2 ch[4][4];
#pragma unroll
  for (int r = 0; r < 4; ++r) {
    float4 c = coef[oc * 4 + r];
    _Float16 x0 = (_Float16)c.x, x1 = (_Float16)c.y,
             x2 = (_Float16)c.z, x3 = (_Float16)c.w;
    ch[r][0][0] = x0; ch[r][0][1] = x0;
    ch[r][1][0] = x1; ch[r][1][1] = x1;
    ch[r][2][0] = x2; ch[r][2][1] = x2;
    ch[r][3][0] = x3; ch[r][3][1] = x3;
  }

#pragma unroll
  for (int it = 0; it < ITER; ++it) {
    int pos = lane + it * TPO;
    int pw = pos % PW, ph = pos / PW;
    h2 o01[2];
#pragma unroll
    for (int py = 0; py < 2; ++py) {
      int pbase = (2 * ph + py) * Wp + 2 * pw;
      h2 lv[8];
#pragma unroll
      for (int l = 0; l < 8; ++l) lv[l] = in[toff[l] + pbase];
      h2 t0 = gateh(ch[0], lv[0], lv[1]);
      h2 t1 = gateh(ch[1], lv[2], lv[3]);
      h2 t2 = gateh(ch[2], lv[4], lv[5]);
      h2 t3 = gateh(ch[3], lv[6], lv[7]);
      h2 u0 = gateh(ch[1], t0, t1);
      h2 u1 = gateh(ch[2], t2, t3);
      o01[py] = gateh(ch[3], u0, u1);
    }
    _Float16 m0 = o01[0][0] > o01[1][0] ? o01[0][0] : o01[1][0];
    _Float16 m1 = o01[0][1] > o01[1][1] ? o01[0][1] : o01[1][1];
    _Float16 v = m0 > m1 ? m0 : m1;
    if (OUTDUP) {
      h16* oh = (h16*)outD;
      int cell = oc * OPS + (ph + 1) * OWp + (pw + 1);
      oh[2 * cell] = v;      // lo of (ph+1, pw+1)
      oh[2 * cell - 1] = v;  // hi of (ph+1, pw)
    } else {
      outP[oc * NPOS + ph * PW + pw] = v;
    }
  }
}

// Megakernel: 256 blocks x 1024 threads; pair (bid>>1)=batch elem, role=bid&1.
// Both blocks compute the full tower redundantly; FC classes split 5/5.
__global__ __launch_bounds__(1024) void mega(
    const float* __restrict__ x, const float4* __restrict__ coefC,
    const int* __restrict__ l1, const int* __restrict__ l2,
    const int* __restrict__ l3, const int* __restrict__ l4,
    const unsigned short* __restrict__ midx16,
    const _Float16* __restrict__ mcoefh, float* __restrict__ out) {
  __shared__ __align__(16) h2 XB[9 * 1157];    // 41,652B  [9][34x34 +1]
  __shared__ __align__(16) h2 S1[32 * 325];    // 41,600B  [32][18x18 +1]
  __shared__ __align__(16) h2 S2[128 * 101];   // 51,712B  [128][10x10 +1]
  __shared__ __align__(16) h16 S3[512 * 16];   // 16,384B  plain [512][4][4]
  __shared__ __align__(16) h16 S4[1024 * 4];   //  8,192B  plain [1024][2][2]
  __shared__ float red[16][5];
  int tid = threadIdx.x;
  int b = blockIdx.x >> 1;
  int role = blockIdx.x & 1;

  // ---- phase 0: zero S1/S2 (halos incl.) + binarize x -> XB dup-padded ----
  {
    float4* z1 = (float4*)S1;  // 2600 float4
    float4* z2 = (float4*)S2;  // 3232 float4
    float4 zz = make_float4(0.f, 0.f, 0.f, 0.f);
    for (int i = tid; i < 2600; i += 1024) z1[i] = zz;
    for (int i = tid; i < 3232; i += 1024) z2[i] = zz;
  }
  const float* xg = x + b * 3072;
  for (int cell = tid; cell < 9 * 1157; cell += 1024) {
    int c9 = cell / 1157;
    int rem = cell - c9 * 1157;
    if (rem >= 1156) continue;  // plane pad cell, never read
    int i = rem / 34, j = rem - 34 * (rem / 34);
    int th = c9 / 3, c = c9 - 3 * th;
    float thr = (float)(th + 1) * 0.25f;
    _Float16 lo = (_Float16)0, hi = (_Float16)0;
    if (i >= 1 && i <= 32) {
      const float* row = xg + c * 1024 + (i - 1) * 32;
      if (j >= 1 && j <= 32) lo = (_Float16)((row[j - 1] > thr) ? 1.f : 0.f);
      if (j <= 31)           hi = (_Float16)((row[j] > thr) ? 1.f : 0.f);
    }
    XB[cell] = h2{lo, hi};
  }
  __syncthreads();

  // ---- conv tower (redundant across the pair; no wall-time cost) ----
  stage<9, 32, 32, 32, 1157, 325, true>(XB, S1, nullptr, l1, coefC, tid);
  __syncthreads();
  stage<32, 16, 16, 128, 325, 101, true>(S1, S2, nullptr, l2, coefC + 128, tid);
  __syncthreads();
  stage<128, 8, 8, 512, 101, 0, false>(S2, nullptr, S3, l3, coefC + 640, tid);
  __syncthreads();

  // ---- stage 4: plain in [512][4][4] with bounds checks, 1 thread/oc ----
  {
    int oc = tid;
    int cc[8], di[8], dj[8];
#pragma unroll
    for (int l = 0; l < 8; ++l) {
      int k = l4[oc * 8 + l];
      cc[l] = k / 9;
      int p = k - 9 * cc[l];
      di[l] = p / 3;
      dj[l] = p - 3 * di[l];
    }
    float4 c0 = coefC[2688 + oc * 4 + 0];
    float4 c1 = coefC[2688 + oc * 4 + 1];
    float4 c2 = coefC[2688 + oc * 4 + 2];
    float4 c3 = coefC[2688 + oc * 4 + 3];
#pragma unroll
    for (int pos = 0; pos < 4; ++pos) {
      int pw = pos & 1, ph = pos >> 1;
      float best = -1e30f;
#pragma unroll
      for (int py = 0; py < 2; ++py) {
#pragma unroll
        for (int px = 0; px < 2; ++px) {
          int i = 2 * ph + py, j = 2 * pw + px;
          float lv[8];
#pragma unroll
          for (int l = 0; l < 8; ++l) {
            int ii = i + di[l] - 1, jj = j + dj[l] - 1;
            float v = 0.f;
            if ((unsigned)ii < 4u && (unsigned)jj < 4u)
              v = (float)S3[cc[l] * 16 + ii * 4 + jj];
            lv[l] = v;
          }
          float t0 = gate_eval(c0, lv[0], lv[1]);
          float t1 = gate_eval(c1, lv[2], lv[3]);
          float t2 = gate_eval(c2, lv[4], lv[5]);
          float t3 = gate_eval(c3, lv[6], lv[7]);
          float u0 = gate_eval(c1, t0, t1);
          float u1 = gate_eval(c2, t2, t3);
          best = fmaxf(best, gate_eval(c3, u0, u1));
        }
      }
      S4[oc * 4 + pos] = (h16)best;
    }
  }
  __syncthreads();

  // ---- fused FC, 5 classes per block (role-split); o = cls*1024 + tid ----
  const uint4* mi = (const uint4*)midx16;
  const uint2* mc = (const uint2*)mcoefh;
  int wid = tid >> 6;
#pragma unroll
  for (int k = 0; k < 5; ++k) {
    int o = (role * 5 + k) * 1024 + tid;
    uint4 I = mi[o];
    const uint2* cfp = mc + o * 7;
    float L0 = gate_eval(dec_cf(cfp[0]), (float)S4[I.x & 0xffff], (float)S4[I.x >> 16]);
    float L1 = gate_eval(dec_cf(cfp[1]), (float)S4[I.y & 0xffff], (float)S4[I.y >> 16]);
    float L2 = gate_eval(dec_cf(cfp[2]), (float)S4[I.z & 0xffff], (float)S4[I.z >> 16]);
    float L3 = gate_eval(dec_cf(cfp[3]), (float)S4[I.w & 0xffff], (float)S4[I.w >> 16]);
    float M0 = gate_eval(dec_cf(cfp[4]), L0, L1);
    float M1 = gate_eval(dec_cf(cfp[5]), L2, L3);
    float y = gate_eval(dec_cf(cfp[6]), M0, M1);
#pragma unroll
    for (int m = 32; m > 0; m >>= 1) y += __shfl_xor(y, m, 64);
    if ((tid & 63) == 0) red[wid][k] = y;
  }
  __syncthreads();
  if (tid < 5) {
    float s = 0.f;
#pragma unroll
    for (int w = 0; w < 16; ++w) s += red[w][tid];
    out[b * 10 + role * 5 + tid] = s * 0.1f;
  }
}

extern "C" void kernel_launch(void* const* d_in, const int* in_sizes, int n_in,
                              void* d_out, int out_size, void* d_ws, size_t ws_size,
                              hipStream_t stream) {
  const float* x   = (const float*)d_in[0];
  const float* w1  = (const float*)d_in[1];
  const float* w2  = (const float*)d_in[2];
  const float* w3  = (const float*)d_in[3];
  const float* w4  = (const float*)d_in[4];
  const float* fw1 = (const float*)d_in[5];
  const float* fw2 = (const float*)d_in[6];
  const float* fw3 = (const float*)d_in[7];
  const int* l1  = (const int*)d_in[8];
  const int* l2  = (const int*)d_in[9];
  const int* l3  = (const int*)d_in[10];
  const int* l4  = (const int*)d_in[11];
  const int* ca1 = (const int*)d_in[12];
  const int* cb1 = (const int*)d_in[13];
  const int* ca2 = (const int*)d_in[14];
  const int* cb2 = (const int*)d_in[15];
  const int* ca3 = (const int*)d_in[16];
  const int* cb3 = (const int*)d_in[17];

  char* ws = (char*)d_ws;
  float4*         coefC  = (float4*)ws;                      // 108,544 B
  unsigned short* midx16 = (unsigned short*)(ws + 108544);   // 163,840 B
  _Float16*       mcoefh = (_Float16*)(ws + 108544 + 163840);// 573,440 B

  prep_all<<<307, 256, 0, stream>>>(w1, w2, w3, w4, fw1, fw2, fw3,
                                    ca1, cb1, ca2, cb2, ca3, cb3,
                                    coefC, midx16, mcoefh);
  mega<<<256, 1024, 0, stream>>>(x, coefC, l1, l2, l3, l4, midx16, mcoefh,
                                 (float*)d_out);
}

// Round 15
// 58.950 us; speedup vs baseline: 1.4490x; 1.0094x over previous
//
#include <hip/hip_runtime.h>
#include <math.h>

// ---------------------------------------------------------------------------
// ConvLogicNetCIFAR forward. R15 = R14 (59.5us: pair-redundant blocks, FC
// split 5/5) + LDS-pipe reduction. R14 counters: VALUBusy 35%, conflicts
// 9.3M cyc, ~560K LDS lane-ops/block -> LDS pipe is the critical resource.
//  1) stages 1-3: paired-row tap reads off one base (p[0], p[Wp]) ->
//     ds_read2_b32-fusable; halves LDS instruction count.
//  2) stage 4: was 128 scalar bounds-checked u16 reads/thread. Stage 3 now
//     writes dup-style S3d[512][4][5] h2 (cell j = (v[j-1], v[j])) ->
//     stage 4 = 64 predicated dword reads (row bounds only; col cell
//     2pw+dj always in [0,4]) + packed-h2 gates. S3d ALIASES dead XB;
//     its col-0 pads zeroed during the stage-2 phase (no extra barrier).
//  3) S3-plain dropped: LDS 160KB -> 143KB.
// Structure: 256 blocks x 1024 thr = 2/batch elem; both redundantly compute
// the tower (idle-CU redundancy is free; cross-block sync = L2 flush, R8/R10),
// then split FC classes 5/5. Gate: c0+c1*a+c2*b+c3*ab, c=softmax(w)@COEF.
// Tree quirk: off=2^lvl-1 -> level0 rows0..3, level1 rows1..2, level2 row3.
// ---------------------------------------------------------------------------

typedef _Float16 h16;
typedef _Float16 h2 __attribute__((ext_vector_type(2)));

__constant__ float c_coef_tbl[16][4] = {
    {0, 0, 0, 0}, {0, 0, 0, 1}, {0, 1, 0, -1}, {0, 1, 0, 0},
    {0, 0, 1, -1}, {0, 0, 1, 0}, {0, 1, 1, -2}, {0, 1, 1, -1},
    {1, -1, -1, 1}, {1, -1, -1, 2}, {1, 0, -1, 0}, {1, 0, -1, 1},
    {1, -1, 0, 0}, {1, -1, 0, 1}, {1, 0, 0, -1}, {1, 0, 0, 0}};

__device__ __forceinline__ float4 softmax_coef(const float* __restrict__ wr) {
  float m = -1e30f;
#pragma unroll
  for (int k = 0; k < 16; ++k) m = fmaxf(m, wr[k]);
  float e[16], s = 0.f;
#pragma unroll
  for (int k = 0; k < 16; ++k) { e[k] = __expf(wr[k] - m); s += e[k]; }
  float inv = 1.f / s;
  float c0 = 0.f, c1 = 0.f, c2 = 0.f, c3 = 0.f;
#pragma unroll
  for (int k = 0; k < 16; ++k) {
    c0 += e[k] * c_coef_tbl[k][0];
    c1 += e[k] * c_coef_tbl[k][1];
    c2 += e[k] * c_coef_tbl[k][2];
    c3 += e[k] * c_coef_tbl[k][3];
  }
  return make_float4(c0 * inv, c1 * inv, c2 * inv, c3 * inv);
}

__device__ __forceinline__ float gate_eval(float4 c, float a, float b) {
  return c.x + c.y * a + c.z * b + c.w * (a * b);
}
__device__ __forceinline__ float4 dec_cf(uint2 u) {
  h2 p0, p1;
  *(unsigned*)&p0 = u.x;
  *(unsigned*)&p1 = u.y;
  return make_float4((float)p0[0], (float)p0[1], (float)p1[0], (float)p1[1]);
}
__device__ __forceinline__ h2 gateh(const h2* c, h2 a, h2 b) {
  return c[0] + c[1] * a + c[2] * b + c[3] * (a * b);
}
__device__ __forceinline__ h2 tree8(const h2 (&ch)[4][4], const h2* lv) {
  h2 t0 = gateh(ch[0], lv[0], lv[1]);
  h2 t1 = gateh(ch[1], lv[2], lv[3]);
  h2 t2 = gateh(ch[2], lv[4], lv[5]);
  h2 t3 = gateh(ch[3], lv[6], lv[7]);
  h2 u0 = gateh(ch[1], t0, t1);
  h2 u1 = gateh(ch[2], t2, t3);
  return gateh(ch[3], u0, u1);
}
__device__ __forceinline__ h2 pkmax(h2 a, h2 b) {
  h2 r;
  r[0] = a[0] > b[0] ? a[0] : b[0];
  r[1] = a[1] > b[1] ? a[1] : b[1];
  return r;
}
__device__ __forceinline__ void splat_ch(const float4* __restrict__ coef, int oc,
                                         h2 (&ch)[4][4]) {
#pragma unroll
  for (int r = 0; r < 4; ++r) {
    float4 c = coef[oc * 4 + r];
    _Float16 x0 = (_Float16)c.x, x1 = (_Float16)c.y,
             x2 = (_Float16)c.z, x3 = (_Float16)c.w;
    ch[r][0][0] = x0; ch[r][0][1] = x0;
    ch[r][1][0] = x1; ch[r][1][1] = x1;
    ch[r][2][0] = x2; ch[r][2][1] = x2;
    ch[r][3][0] = x3; ch[r][3][1] = x3;
  }
}

// prep: g<71680 FC tree (o=g/7, s=g%7 -> fp16 coefs mcoefh[o*28+s*4], u16
// midx16[o*8..]); g in [71680,78464) conv gate coefs float4
// (w1[0,128) w2[128,640) w3[640,2688) w4[2688,6784); gate gg -> row oc*7+(gg&3)).
__global__ void prep_all(const float* __restrict__ w1, const float* __restrict__ w2,
                         const float* __restrict__ w3, const float* __restrict__ w4,
                         const float* __restrict__ fw1, const float* __restrict__ fw2,
                         const float* __restrict__ fw3,
                         const int* __restrict__ ca1, const int* __restrict__ cb1,
                         const int* __restrict__ ca2, const int* __restrict__ cb2,
                         const int* __restrict__ ca3, const int* __restrict__ cb3,
                         float4* __restrict__ coefC,
                         unsigned short* __restrict__ midx16,
                         _Float16* __restrict__ mcoefh) {
  int g = blockIdx.x * blockDim.x + threadIdx.x;
  if (g < 71680) {
    int o = g / 7;
    int s = g - o * 7;
    float4 c;
    if (s < 4) {
      int k = (s < 2) ? ca3[o] : cb3[o];
      int j = (s & 1) ? cb2[k] : ca2[k];
      midx16[o * 8 + s * 2]     = (unsigned short)ca1[j];
      midx16[o * 8 + s * 2 + 1] = (unsigned short)cb1[j];
      c = softmax_coef(fw1 + j * 16);
    } else if (s < 6) {
      int k = (s == 4) ? ca3[o] : cb3[o];
      c = softmax_coef(fw2 + k * 16);
    } else {
      c = softmax_coef(fw3 + o * 16);
    }
    _Float16* mc = mcoefh + o * 28 + s * 4;
    mc[0] = (_Float16)c.x; mc[1] = (_Float16)c.y;
    mc[2] = (_Float16)c.z; mc[3] = (_Float16)c.w;
  } else if (g < 78464) {
    int gg = g - 71680;
    int base = gg;
    const float* w;
    if (gg < 128)       {             w = w1; }
    else if (gg < 640)  { gg -= 128;  w = w2; }
    else if (gg < 2688) { gg -= 640;  w = w3; }
    else                { gg -= 2688; w = w4; }
    coefC[base] = softmax_coef(w + ((gg >> 2) * 7 + (gg & 3)) * 16);
  }
}

// Conv tree + orpool, LDS->LDS dup cells, paired-row reads (ds_read2-fusable).
// in: [C] planes, row stride Wp=W+2, plane stride IPS.
// out: dup cells, plane stride OPS, row stride OW, vertical halo VH rows.
template <int C, int H, int W, int OC, int IPS, int OPS, int OW, int VH>
__device__ void stage(const h2* __restrict__ in, h2* __restrict__ outD,
                      const int* __restrict__ leaf,
                      const float4* __restrict__ coef, int tid) {
  constexpr int Wp = W + 2;
  constexpr int PH = H / 2, PW = W / 2;
  constexpr int NPOS = PH * PW;
  constexpr int TPO = 1024 / OC;
  constexpr int ITER = NPOS / TPO;

  int oc = tid / TPO;
  int lane = tid % TPO;

  int toff[8];
#pragma unroll
  for (int l = 0; l < 8; ++l) {
    int k = leaf[oc * 8 + l];
    int cc = k / 9;
    int p = k - 9 * cc;
    int di = p / 3;
    int dj = p - 3 * di;
    toff[l] = cc * IPS + di * Wp + dj;
  }
  h2 ch[4][4];
  splat_ch(coef, oc, ch);

#pragma unroll
  for (int it = 0; it < ITER; ++it) {
    int pos = lane + it * TPO;
    int pw = pos % PW, ph = pos / PW;
    int pb0 = (2 * ph) * Wp + 2 * pw;
    h2 A[8], B[8];
#pragma unroll
    for (int l = 0; l < 8; ++l) {
      const h2* p = in + toff[l] + pb0;
      A[l] = p[0];      // py=0 row
      B[l] = p[Wp];     // py=1 row (const dword offset -> ds_read2)
    }
    h2 oA = tree8(ch, A);
    h2 oB = tree8(ch, B);
    h2 pm = pkmax(oA, oB);
    _Float16 v = pm[0] > pm[1] ? pm[0] : pm[1];
    h16* oh = (h16*)outD;
    int cell = oc * OPS + (ph + VH) * OW + (pw + 1);
    oh[2 * cell] = v;      // lo of cell (pw+1)  = v[pw]
    oh[2 * cell - 1] = v;  // hi of cell (pw)    = v[pw]
  }
}

// Megakernel: 256 blocks x 1024 threads; pair (bid>>1)=batch elem, role=bid&1.
__global__ __launch_bounds__(1024) void mega(
    const float* __restrict__ x, const float4* __restrict__ coefC,
    const int* __restrict__ l1, const int* __restrict__ l2,
    const int* __restrict__ l3, const int* __restrict__ l4,
    const unsigned short* __restrict__ midx16,
    const _Float16* __restrict__ mcoefh, float* __restrict__ out) {
  __shared__ __align__(16) h2 XB[9 * 1157];    // 41,652B  [9] rows(34)x34 +1
  __shared__ __align__(16) h2 S1[32 * 325];    // 41,600B  [32][18x18 +1]
  __shared__ __align__(16) h2 S2[128 * 101];   // 51,712B  [128][10x10 +1]
  __shared__ __align__(16) h16 S4[1024 * 4];   //  8,192B  plain [1024][2][2]
  __shared__ float red[16][5];
  h2* S3d = XB;  // stage3 dup out [512][4][5] = 10,240 h2, aliases dead XB
  int tid = threadIdx.x;
  int b = blockIdx.x >> 1;
  int role = blockIdx.x & 1;

  // ---- phase 0: zero S1/S2 (halos incl.) + binarize x -> XB dup-padded ----
  {
    float4* z1 = (float4*)S1;  // 2600 float4
    float4* z2 = (float4*)S2;  // 3232 float4
    float4 zz = make_float4(0.f, 0.f, 0.f, 0.f);
    for (int i = tid; i < 2600; i += 1024) z1[i] = zz;
    for (int i = tid; i < 3232; i += 1024) z2[i] = zz;
  }
  const float* xg = x + b * 3072;
  for (int cell = tid; cell < 9 * 1157; cell += 1024) {
    int c9 = cell / 1157;
    int rem = cell - c9 * 1157;
    if (rem >= 1156) continue;  // plane pad cell, never read
    int i = rem / 34, j = rem - 34 * (rem / 34);
    int th = c9 / 3, c = c9 - 3 * th;
    float thr = (float)(th + 1) * 0.25f;
    _Float16 lo = (_Float16)0, hi = (_Float16)0;
    if (i >= 1 && i <= 32) {
      const float* row = xg + c * 1024 + (i - 1) * 32;
      if (j >= 1 && j <= 32) lo = (_Float16)((row[j - 1] > thr) ? 1.f : 0.f);
      if (j <= 31)           hi = (_Float16)((row[j] > thr) ? 1.f : 0.f);
    }
    XB[cell] = h2{lo, hi};
  }
  __syncthreads();

  // ---- stage 1: XB -> S1 ----
  stage<9, 32, 32, 32, 1157, 325, 18, 1>(XB, S1, l1, coefC, tid);
  __syncthreads();

  // ---- stage 2: S1 -> S2; also zero S3d's col-0 pad cells (XB now dead) ----
  for (int i = tid; i < 2048; i += 1024)   // cells oc*20 + ph*5, oc<512, ph<4
    S3d[(i >> 2) * 20 + (i & 3) * 5] = h2{(_Float16)0, (_Float16)0};
  stage<32, 16, 16, 128, 325, 101, 10, 1>(S1, S2, l2, coefC + 128, tid);
  __syncthreads();

  // ---- stage 3: S2 -> S3d dup [512][4][5], no vertical halo ----
  stage<128, 8, 8, 512, 101, 20, 5, 0>(S2, S3d, l3, coefC + 640, tid);
  __syncthreads();

  // ---- stage 4: S3d dup reads (row-bounds predicated), 1 thread/oc ----
  {
    int oc = tid;
    int boff[8], dI[8];
#pragma unroll
    for (int l = 0; l < 8; ++l) {
      int k = l4[oc * 8 + l];
      int cc = k / 9;
      int p = k - 9 * cc;
      int di = p / 3;
      int dj = p - 3 * di;
      dI[l] = di;
      boff[l] = cc * 20 + dj;   // + i*5 + 2*pw at use site
    }
    h2 ch[4][4];
    splat_ch(coefC + 2688, oc, ch);
#pragma unroll
    for (int pos = 0; pos < 4; ++pos) {
      int pw = pos & 1, ph = pos >> 1;
      h2 o01[2];
#pragma unroll
      for (int py = 0; py < 2; ++py) {
        h2 lv[8];
#pragma unroll
        for (int l = 0; l < 8; ++l) {
          int i = 2 * ph + py + dI[l] - 1;
          h2 v = h2{(_Float16)0, (_Float16)0};
          if ((unsigned)i < 4u) v = S3d[boff[l] + i * 5 + 2 * pw];
          lv[l] = v;
        }
        o01[py] = tree8(ch, lv);
      }
      h2 pm = pkmax(o01[0], o01[1]);
      S4[oc * 4 + pos] = pm[0] > pm[1] ? pm[0] : pm[1];
    }
  }
  __syncthreads();

  // ---- fused FC, 5 classes per block (role-split); o = cls*1024 + tid ----
  const uint4* mi = (const uint4*)midx16;
  const uint2* mc = (const uint2*)mcoefh;
  int wid = tid >> 6;
#pragma unroll
  for (int k = 0; k < 5; ++k) {
    int o = (role * 5 + k) * 1024 + tid;
    uint4 I = mi[o];
    const uint2* cfp = mc + o * 7;
    float L0 = gate_eval(dec_cf(cfp[0]), (float)S4[I.x & 0xffff], (float)S4[I.x >> 16]);
    float L1 = gate_eval(dec_cf(cfp[1]), (float)S4[I.y & 0xffff], (float)S4[I.y >> 16]);
    float L2 = gate_eval(dec_cf(cfp[2]), (float)S4[I.z & 0xffff], (float)S4[I.z >> 16]);
    float L3 = gate_eval(dec_cf(cfp[3]), (float)S4[I.w & 0xffff], (float)S4[I.w >> 16]);
    float M0 = gate_eval(dec_cf(cfp[4]), L0, L1);
    float M1 = gate_eval(dec_cf(cfp[5]), L2, L3);
    float y = gate_eval(dec_cf(cfp[6]), M0, M1);
#pragma unroll
    for (int m = 32; m > 0; m >>= 1) y += __shfl_xor(y, m, 64);
    if ((tid & 63) == 0) red[wid][k] = y;
  }
  __syncthreads();
  if (tid < 5) {
    float s = 0.f;
#pragma unroll
    for (int w = 0; w < 16; ++w) s += red[w][tid];
    out[b * 10 + role * 5 + tid] = s * 0.1f;
  }
}

extern "C" void kernel_launch(void* const* d_in, const int* in_sizes, int n_in,
                              void* d_out, int out_size, void* d_ws, size_t ws_size,
                              hipStream_t stream) {
  const float* x   = (const float*)d_in[0];
  const float* w1  = (const float*)d_in[1];
  const float* w2  = (const float*)d_in[2];
  const float* w3  = (const float*)d_in[3];
  const float* w4  = (const float*)d_in[4];
  const float* fw1 = (const float*)d_in[5];
  const float* fw2 = (const float*)d_in[6];
  const float* fw3 = (const float*)d_in[7];
  const int* l1  = (const int*)d_in[8];
  const int* l2  = (const int*)d_in[9];
  const int* l3  = (const int*)d_in[10];
  const int* l4  = (const int*)d_in[11];
  const int* ca1 = (const int*)d_in[12];
  const int* cb1 = (const int*)d_in[13];
  const int* ca2 = (const int*)d_in[14];
  const int* cb2 = (const int*)d_in[15];
  const int* ca3 = (const int*)d_in[16];
  const int* cb3 = (const int*)d_in[17];

  char* ws = (char*)d_ws;
  float4*         coefC  = (float4*)ws;                      // 108,544 B
  unsigned short* midx16 = (unsigned short*)(ws + 108544);   // 163,840 B
  _Float16*       mcoefh = (_Float16*)(ws + 108544 + 163840);// 573,440 B

  prep_all<<<307, 256, 0, stream>>>(w1, w2, w3, w4, fw1, fw2, fw3,
                                    ca1, cb1, ca2, cb2, ca3, cb3,
                                    coefC, midx16, mcoefh);
  mega<<<256, 1024, 0, stream>>>(x, coefC, l1, l2, l3, l4, midx16, mcoefh,
                                 (float*)d_out);
}